// Round 1
// baseline (333.534 us; speedup 1.0000x reference)
//
#include <hip/hip_runtime.h>
#include <math.h>

#define N_NODES 50000
#define N_EDGES 400000
#define F_IN 32
#define NUM_GRAPHS 64

// ---------------------------------------------------------------------------
// Factorized NNConv:
//   msg[e,o] = sum_j relu(a_e*w1_j+b1_j) * P[src,j,o] + Q[src,o]
//   P[n,j,o] = sum_i x[n,i]*w2[j, i*O+o]  -- node-level GEMM, never per-edge
// P1 layout per node (192 cols): [0,160)=P(j,o), [160,176)=Q, [176,192)=x@root
// P2 layout per node (384 cols): [0,320)=P(j,o), [320,352)=Q, [352,384)=h1@root
// ---------------------------------------------------------------------------

__global__ __launch_bounds__(256) void k1_p1(const float* __restrict__ x,
        const float* __restrict__ w2, const float* __restrict__ b2,
        const float* __restrict__ root, float* __restrict__ P) {
    __shared__ float Wl[32][192];
    __shared__ float xl[16][32];
    int t = threadIdx.x;
    for (int idx = t; idx < 32 * 192; idx += 256) {
        int i = idx / 192, c = idx % 192;
        float w;
        if (c < 160)      { int j = c >> 4;  int o = c & 15;  w = w2[j * 512 + i * 16 + o]; }
        else if (c < 176) { int o = c - 160; w = b2[i * 16 + o]; }
        else              { int o = c - 176; w = root[i * 16 + o]; }
        Wl[i][c] = w;
    }
    int n0 = blockIdx.x * 16;
    for (int idx = t; idx < 16 * 32; idx += 256) {
        int nl = idx >> 5, i = idx & 31;
        int n = n0 + nl;
        xl[nl][i] = (n < N_NODES) ? x[n * 32 + i] : 0.f;
    }
    __syncthreads();
    int nl = t >> 4, cs = t & 15;
    int n = n0 + nl;
    if (n >= N_NODES) return;
    float acc[12];
#pragma unroll
    for (int k = 0; k < 12; k++) acc[k] = 0.f;
#pragma unroll
    for (int i = 0; i < 32; i++) {
        float xv = xl[nl][i];
#pragma unroll
        for (int k = 0; k < 12; k++) acc[k] += xv * Wl[i][cs + 16 * k];
    }
#pragma unroll
    for (int k = 0; k < 12; k++) P[(size_t)n * 192 + cs + 16 * k] = acc[k];
}

__global__ __launch_bounds__(256) void k4_p2(const float* __restrict__ h1,
        const float* __restrict__ w2, const float* __restrict__ b2,
        const float* __restrict__ root, float* __restrict__ P) {
    __shared__ float Wl[16][384];
    __shared__ float hl[16][16];
    int t = threadIdx.x;
    for (int idx = t; idx < 16 * 384; idx += 256) {
        int i = idx / 384, c = idx % 384;
        float w;
        if (c < 320)      { int j = c >> 5;  int o = c & 31;  w = w2[j * 512 + i * 32 + o]; }
        else if (c < 352) { int o = c - 320; w = b2[i * 32 + o]; }
        else              { int o = c - 352; w = root[i * 32 + o]; }
        Wl[i][c] = w;
    }
    int n0 = blockIdx.x * 16;
    for (int idx = t; idx < 16 * 16; idx += 256) {
        int nl = idx >> 4, i = idx & 15;
        int n = n0 + nl;
        hl[nl][i] = (n < N_NODES) ? h1[n * 16 + i] : 0.f;
    }
    __syncthreads();
    int nl = t >> 4, cs = t & 15;
    int n = n0 + nl;
    if (n >= N_NODES) return;
    float acc[24];
#pragma unroll
    for (int k = 0; k < 24; k++) acc[k] = 0.f;
#pragma unroll
    for (int i = 0; i < 16; i++) {
        float hv = hl[nl][i];
#pragma unroll
        for (int k = 0; k < 24; k++) acc[k] += hv * Wl[i][cs + 16 * k];
    }
#pragma unroll
    for (int k = 0; k < 24; k++) P[(size_t)n * 384 + cs + 16 * k] = acc[k];
}

__global__ __launch_bounds__(256) void k2_edge1(const float* __restrict__ P,
        const int* __restrict__ src, const int* __restrict__ dst,
        const float* __restrict__ ea, const float* __restrict__ w1,
        const float* __restrict__ b1, float* __restrict__ agg,
        float* __restrict__ cnt) {
    int t = threadIdx.x;
    int e = blockIdx.x * 16 + (t >> 4);
    int o = t & 15;
    if (e >= N_EDGES) return;
    float a = ea[e];
    int s = src[e], d = dst[e];
    const float* Pr = P + (size_t)s * 192;
    float m = Pr[160 + o];
#pragma unroll
    for (int j = 0; j < 10; j++) {
        float r = fmaxf(a * w1[j] + b1[j], 0.f);
        m += r * Pr[j * 16 + o];
    }
    atomicAdd(agg + d * 16 + o, m);
    if (o == 0) atomicAdd(cnt + d, 1.0f);
}

__global__ __launch_bounds__(256) void k5_edge2(const float* __restrict__ P,
        const int* __restrict__ src, const int* __restrict__ dst,
        const float* __restrict__ ea, const float* __restrict__ w1,
        const float* __restrict__ b1, float* __restrict__ agg) {
    int t = threadIdx.x;
    int e = blockIdx.x * 8 + (t >> 5);
    int o = t & 31;
    if (e >= N_EDGES) return;
    float a = ea[e];
    int s = src[e], d = dst[e];
    const float* Pr = P + (size_t)s * 384;
    float m = Pr[320 + o];
#pragma unroll
    for (int j = 0; j < 10; j++) {
        float r = fmaxf(a * w1[j] + b1[j], 0.f);
        m += r * Pr[j * 32 + o];
    }
    atomicAdd(agg + d * 32 + o, m);
}

__global__ void k3_node1(const float* __restrict__ agg, const float* __restrict__ cnt,
        const float* __restrict__ P, const float* __restrict__ bias,
        float* __restrict__ h1) {
    int gid = blockIdx.x * 256 + threadIdx.x;
    if (gid >= N_NODES * 16) return;
    int n = gid >> 4, o = gid & 15;
    float c = fmaxf(cnt[n], 1.0f);
    float v = agg[gid] / c + P[(size_t)n * 192 + 176 + o] + bias[o];
    h1[gid] = v > 0.f ? v : expm1f(v);
}

__global__ void k6_node2(const float* __restrict__ agg, const float* __restrict__ cnt,
        const float* __restrict__ P, const float* __restrict__ bias,
        float* __restrict__ h2) {
    int gid = blockIdx.x * 256 + threadIdx.x;
    if (gid >= N_NODES * 32) return;
    int n = gid >> 5, o = gid & 31;
    float c = fmaxf(cnt[n], 1.0f);
    float v = agg[gid] / c + P[(size_t)n * 384 + 352 + o] + bias[o];
    h2[gid] = v > 0.f ? v : expm1f(v);
}

// batch is sorted -> each graph is a contiguous node range; binary search, no atomics
__global__ __launch_bounds__(256) void k7_pool(const float* __restrict__ h2,
        const int* __restrict__ batch, float* __restrict__ gp) {
    int g = blockIdx.x;
    int t = threadIdx.x;
    int lo = 0, hi = N_NODES;
    while (lo < hi) { int mid = (lo + hi) >> 1; if (batch[mid] < g) lo = mid + 1; else hi = mid; }
    int start = lo;
    hi = N_NODES;
    while (lo < hi) { int mid = (lo + hi) >> 1; if (batch[mid] < g + 1) lo = mid + 1; else hi = mid; }
    int end = lo;
    int o = t & 31, ch = t >> 5;
    float s = 0.f;
    for (int n = start + ch; n < end; n += 8) s += h2[(size_t)n * 32 + o];
    __shared__ float red[8][32];
    red[ch][o] = s;
    __syncthreads();
    if (t < 32) {
        float tot = 0.f;
#pragma unroll
        for (int c = 0; c < 8; c++) tot += red[c][t];
        gp[g * 32 + t] = tot / fmaxf((float)(end - start), 1.0f);
    }
}

__global__ __launch_bounds__(256) void k8_head(const float* __restrict__ gp,
        const float* __restrict__ fc1w, const float* __restrict__ fc1b,
        const float* __restrict__ fc2w, const float* __restrict__ fc2b,
        float* __restrict__ out) {
    __shared__ float gl[64][32];
    __shared__ float w1l[32][64];
    __shared__ float hl[64][64];
    __shared__ float zl[64][2];
    int t = threadIdx.x;
    for (int idx = t; idx < 64 * 32; idx += 256) gl[idx >> 5][idx & 31] = gp[idx];
    for (int idx = t; idx < 32 * 64; idx += 256) w1l[idx >> 6][idx & 63] = fc1w[idx];
    __syncthreads();
    for (int idx = t; idx < 64 * 64; idx += 256) {
        int gg = idx >> 6, c = idx & 63;
        float acc = fc1b[c];
#pragma unroll
        for (int i = 0; i < 32; i++) acc += gl[gg][i] * w1l[i][c];
        hl[gg][c] = acc > 0.f ? acc : expm1f(acc);
    }
    __syncthreads();
    if (t < 128) {
        int gg = t >> 1, k = t & 1;
        float acc = fc2b[k];
#pragma unroll
        for (int c = 0; c < 64; c++) acc += hl[gg][c] * fc2w[c * 2 + k];
        zl[gg][k] = acc;
    }
    __syncthreads();
    if (t < 128) {
        int gg = t >> 1, k = t & 1;
        float z0 = zl[gg][0], z1 = zl[gg][1];
        float m = fmaxf(z0, z1);
        float lse = m + logf(expf(z0 - m) + expf(z1 - m));
        out[t] = zl[gg][k] - lse;
    }
}

extern "C" void kernel_launch(void* const* d_in, const int* in_sizes, int n_in,
                              void* d_out, int out_size, void* d_ws, size_t ws_size,
                              hipStream_t stream) {
    const float* x       = (const float*)d_in[0];
    const int*   ei      = (const int*)d_in[1];
    const float* ea      = (const float*)d_in[2];
    const int*   batch   = (const int*)d_in[3];
    const float* nn1_w1  = (const float*)d_in[4];
    const float* nn1_b1  = (const float*)d_in[5];
    const float* nn1_w2  = (const float*)d_in[6];
    const float* nn1_b2  = (const float*)d_in[7];
    const float* c1_root = (const float*)d_in[8];
    const float* c1_bias = (const float*)d_in[9];
    const float* nn2_w1  = (const float*)d_in[10];
    const float* nn2_b1  = (const float*)d_in[11];
    const float* nn2_w2  = (const float*)d_in[12];
    const float* nn2_b2  = (const float*)d_in[13];
    const float* c2_root = (const float*)d_in[14];
    const float* c2_bias = (const float*)d_in[15];
    const float* fc1w    = (const float*)d_in[16];
    const float* fc1b    = (const float*)d_in[17];
    const float* fc2w    = (const float*)d_in[18];
    const float* fc2b    = (const float*)d_in[19];
    const int* src = ei;
    const int* dst = ei + N_EDGES;

    float* ws = (float*)d_ws;
    size_t off = 0;
    float* P    = ws + off; off += (size_t)N_NODES * 384;   // shared by P1/P2
    float* cnt  = ws + off; off += N_NODES;                 // cnt then agg1: contiguous memset
    float* agg1 = ws + off; off += (size_t)N_NODES * 16;
    float* agg2 = ws + off; off += (size_t)N_NODES * 32;
    float* h1   = ws + off; off += (size_t)N_NODES * 16;
    float* h2   = ws + off; off += (size_t)N_NODES * 32;
    float* gp   = ws + off; off += NUM_GRAPHS * 32;

    hipMemsetAsync(cnt, 0, (size_t)(N_NODES + N_NODES * 16) * sizeof(float), stream);
    hipMemsetAsync(agg2, 0, (size_t)N_NODES * 32 * sizeof(float), stream);

    k1_p1<<<(N_NODES + 15) / 16, 256, 0, stream>>>(x, nn1_w2, nn1_b2, c1_root, P);
    k2_edge1<<<(N_EDGES + 15) / 16, 256, 0, stream>>>(P, src, dst, ea, nn1_w1, nn1_b1, agg1, cnt);
    k3_node1<<<(N_NODES * 16 + 255) / 256, 256, 0, stream>>>(agg1, cnt, P, c1_bias, h1);
    k4_p2<<<(N_NODES + 15) / 16, 256, 0, stream>>>(h1, nn2_w2, nn2_b2, c2_root, P);
    k5_edge2<<<(N_EDGES + 7) / 8, 256, 0, stream>>>(P, src, dst, ea, nn2_w1, nn2_b1, agg2);
    k6_node2<<<(N_NODES * 32 + 255) / 256, 256, 0, stream>>>(agg2, cnt, P, c2_bias, h2);
    k7_pool<<<NUM_GRAPHS, 256, 0, stream>>>(h2, batch, gp);
    k8_head<<<1, 256, 0, stream>>>(gp, fc1w, fc1b, fc2w, fc2b, (float*)d_out);
}